// Round 1
// baseline (1427.976 us; speedup 1.0000x reference)
//
#include <hip/hip_runtime.h>
#include <math.h>

// Problem constants
constexpr int B = 8;
constexpr int H = 16;
constexpr int W = 4096;
constexpr int GH = 8;
constexpr int L = 2048;      // GW
constexpr int DM = 256;
constexpr int DI = 256;
constexpr int NSTATE = 16;
constexpr int NB = 2;
constexpr int NC = 10;
constexpr int LC = 128;      // scan chunk length
constexpr int NCH = L / LC;  // 16 chunks
constexpr int M = B * L;     // 16384 rows for all GEMMs

__device__ __forceinline__ float sigmoidf_(float v) { return 1.f / (1.f + __expf(-v)); }

// ---------------- patch embed: seq[b, t, gh*32+e] = conv2x2(x) + bias ----------------
__global__ void patch_embed(const float* __restrict__ x, const float* __restrict__ pw,
                            const float* __restrict__ pb, float* __restrict__ seq) {
  int idx = blockIdx.x * 256 + threadIdx.x;   // B*L*DM total
  int m = idx & 255;
  int bt = idx >> 8;
  int t = bt & (L - 1);
  int b = bt >> 11;
  int gh = m >> 5, e = m & 31;
  const float* xp = x + ((size_t)b * H + gh * 2) * W + t * 2;
  float acc = pb[e];
  acc = fmaf(xp[0],     pw[e * 4 + 0], acc);
  acc = fmaf(xp[1],     pw[e * 4 + 1], acc);
  acc = fmaf(xp[W],     pw[e * 4 + 2], acc);
  acc = fmaf(xp[W + 1], pw[e * 4 + 3], acc);
  seq[idx] = acc;
}

// ---------------- fp32 GEMM: C[M,N] (+)= A[M,K] @ Bg[K,N], 128x128x16 tiles ----------------
__global__ __launch_bounds__(256) void gemm_f32(
    const float* __restrict__ A, const float* __restrict__ Bg, float* __restrict__ C,
    int N, int K, int accum) {
  __shared__ float As[16][132];   // transposed A tile, padded
  __shared__ float Bs[16][128];
  int tid = threadIdx.x;
  int tx = tid & 15, ty = tid >> 4;
  int m0 = blockIdx.y * 128, n0 = blockIdx.x * 128;
  float acc[8][8] = {};
  for (int k0 = 0; k0 < K; k0 += 16) {
#pragma unroll
    for (int rep = 0; rep < 2; rep++) {
      int mm = (tid >> 2) + rep * 64;
      int kg = (tid & 3) * 4;
      float4 v = *(const float4*)&A[(size_t)(m0 + mm) * K + k0 + kg];
      As[kg + 0][mm] = v.x; As[kg + 1][mm] = v.y;
      As[kg + 2][mm] = v.z; As[kg + 3][mm] = v.w;
    }
#pragma unroll
    for (int rep = 0; rep < 2; rep++) {
      int kk = (tid >> 5) + rep * 8;
      int nn = (tid & 31) * 4;
      int n = n0 + nn;
      float4 v = make_float4(0.f, 0.f, 0.f, 0.f);
      const float* src = Bg + (size_t)(k0 + kk) * N;
      if (n + 3 < N) {
        v = *(const float4*)(src + n);
      } else if (n < N) {
        v.x = src[n];
        if (n + 1 < N) v.y = src[n + 1];
        if (n + 2 < N) v.z = src[n + 2];
      }
      *(float4*)&Bs[kk][nn] = v;
    }
    __syncthreads();
#pragma unroll
    for (int k = 0; k < 16; k++) {
      float a[8], bv[8];
      *(float4*)&a[0] = *(const float4*)&As[k][ty * 4];
      *(float4*)&a[4] = *(const float4*)&As[k][64 + ty * 4];
      *(float4*)&bv[0] = *(const float4*)&Bs[k][tx * 4];
      *(float4*)&bv[4] = *(const float4*)&Bs[k][64 + tx * 4];
#pragma unroll
      for (int i = 0; i < 8; i++)
#pragma unroll
        for (int j = 0; j < 8; j++)
          acc[i][j] = fmaf(a[i], bv[j], acc[i][j]);
    }
    __syncthreads();
  }
#pragma unroll
  for (int i = 0; i < 8; i++) {
    int m = m0 + ty * 4 + (i & 3) + (i >> 2) * 64;
    float* crow = C + (size_t)m * N;
#pragma unroll
    for (int jh = 0; jh < 2; jh++) {
      int n = n0 + tx * 4 + jh * 64;
      if (n + 3 < N) {
        float4 v;
        v.x = acc[i][jh * 4 + 0]; v.y = acc[i][jh * 4 + 1];
        v.z = acc[i][jh * 4 + 2]; v.w = acc[i][jh * 4 + 3];
        if (accum) {
          float4 o = *(const float4*)&crow[n];
          v.x += o.x; v.y += o.y; v.z += o.z; v.w += o.w;
        }
        *(float4*)&crow[n] = v;
      } else {
        for (int q = 0; q < 4; q++) {
          if (n + q < N) {
            float val = acc[i][jh * 4 + q];
            if (accum) val += crow[n + q];
            crow[n + q] = val;
          }
        }
      }
    }
  }
}

// ---------------- causal (dir=0) / anti-causal (dir=1) depthwise conv + silu ----------------
// xi lives in the first 256 columns of xz (row stride 512)
__global__ void conv_silu(const float* __restrict__ xz, const float* __restrict__ cw,
                          const float* __restrict__ cb, float* __restrict__ xc, int dir) {
  int idx = blockIdx.x * 256 + threadIdx.x;   // B*L*DI
  int e = idx & 255;
  int bt = idx >> 8;
  int t = bt & (L - 1);
  int b = bt >> 11;
  float w0 = cw[e * 4 + 0], w1 = cw[e * 4 + 1], w2 = cw[e * 4 + 2], w3 = cw[e * 4 + 3];
  float acc = cb[e];
  const float* base = xz + (size_t)b * L * 512 + e;
  if (dir == 0) {
    if (t >= 3) acc = fmaf(w0, base[(size_t)(t - 3) * 512], acc);
    if (t >= 2) acc = fmaf(w1, base[(size_t)(t - 2) * 512], acc);
    if (t >= 1) acc = fmaf(w2, base[(size_t)(t - 1) * 512], acc);
    acc = fmaf(w3, base[(size_t)t * 512], acc);
  } else {
    if (t + 3 < L) acc = fmaf(w0, base[(size_t)(t + 3) * 512], acc);
    if (t + 2 < L) acc = fmaf(w1, base[(size_t)(t + 2) * 512], acc);
    if (t + 1 < L) acc = fmaf(w2, base[(size_t)(t + 1) * 512], acc);
    acc = fmaf(w3, base[(size_t)t * 512], acc);
  }
  xc[idx] = acc * sigmoidf_(acc);
}

// ---------------- dt = softplus(dt_raw @ W_dt + b_dt), K=16 ----------------
__global__ void dt_softplus(const float* __restrict__ dbl, const float* __restrict__ wdt,
                            const float* __restrict__ bdt, float* __restrict__ dt) {
  int bt = blockIdx.x;
  int e = threadIdx.x;
  __shared__ float r[16];
  if (e < 16) r[e] = dbl[(size_t)bt * 48 + e];
  __syncthreads();
  float acc = bdt[e];
#pragma unroll
  for (int k = 0; k < 16; k++) acc = fmaf(r[k], wdt[k * 256 + e], acc);
  float sp = (acc > 20.f) ? acc : log1pf(expf(acc));
  dt[(size_t)bt * 256 + e] = sp;
}

// ---------------- scan pass A: per-chunk local h recurrence (h0=0), chunk dt-sums ----------------
__global__ __launch_bounds__(256) void scan_passA(
    const float* __restrict__ dt, const float* __restrict__ xc,
    const float* __restrict__ dbl, const float* __restrict__ alog,
    float* __restrict__ hfin, float* __restrict__ sumdt, int dir) {
  int bc = blockIdx.x;
  int b = bc >> 4, c = bc & 15;
  int e = threadIdx.x;
  __shared__ float Bsh[LC][NSTATE];
  float Aa[16];
#pragma unroll
  for (int n = 0; n < 16; n++) Aa[n] = -__expf(alog[e * 16 + n]);
  for (int r = 0; r < LC * NSTATE / 256; r++) {
    int i = r * 256 + e;
    int tloc = i >> 4, n = i & 15;
    int s = c * LC + tloc;
    int w = dir ? (L - 1 - s) : s;
    Bsh[tloc][n] = dbl[((size_t)b * L + w) * 48 + 16 + n];
  }
  __syncthreads();
  float h[16];
#pragma unroll
  for (int n = 0; n < 16; n++) h[n] = 0.f;
  float sdt = 0.f;
  for (int tl = 0; tl < LC; tl++) {
    int s = c * LC + tl;
    int w = dir ? (L - 1 - s) : s;
    size_t base = ((size_t)b * L + w) * 256 + e;
    float d = dt[base];
    float xv = xc[base];
    sdt += d;
    float du = d * xv;
#pragma unroll
    for (int n = 0; n < 16; n++) {
      float dA = __expf(d * Aa[n]);
      h[n] = fmaf(dA, h[n], du * Bsh[tl][n]);
    }
  }
  size_t o = (((size_t)c * B + b) * 256 + e) * 16;
#pragma unroll
  for (int n = 0; n < 16; n++) hfin[o + n] = h[n];
  sumdt[((size_t)c * B + b) * 256 + e] = sdt;
}

// ---------------- scan pass B: sequential chunk combine (tiny) ----------------
__global__ void scan_passB(const float* __restrict__ hfin, const float* __restrict__ sumdt,
                           const float* __restrict__ alog, float* __restrict__ h0) {
  int idx = blockIdx.x * 256 + threadIdx.x;   // B*DI*NSTATE = 32768
  int n = idx & 15;
  int be = idx >> 4;
  int e = be & 255;
  int b = be >> 8;
  float Aa = -__expf(alog[e * 16 + n]);
  float h = 0.f;
  for (int c = 0; c < NCH; c++) {
    size_t o = (((size_t)c * B + b) * 256 + e) * 16 + n;
    h0[o] = h;
    float P = __expf(Aa * sumdt[((size_t)c * B + b) * 256 + e]);
    h = fmaf(P, h, hfin[o]);
  }
}

// ---------------- scan pass C: replay with h0, fuse +xc*D and *silu(z); in-place over dt ----------------
__global__ __launch_bounds__(256) void scan_passC(
    float* __restrict__ dtg, const float* __restrict__ xc,
    const float* __restrict__ dbl, const float* __restrict__ xz,
    const float* __restrict__ alog, const float* __restrict__ dskip,
    const float* __restrict__ h0, int dir) {
  int bc = blockIdx.x;
  int b = bc >> 4, c = bc & 15;
  int e = threadIdx.x;
  __shared__ float Bsh[LC][NSTATE];
  __shared__ float Csh[LC][NSTATE];
  float Aa[16];
#pragma unroll
  for (int n = 0; n < 16; n++) Aa[n] = -__expf(alog[e * 16 + n]);
  for (int r = 0; r < 2 * LC * NSTATE / 256; r++) {
    int i = r * 256 + e;
    int half = i >> 11;
    int rem = i & 2047;
    int tloc = rem >> 4, n = rem & 15;
    int s = c * LC + tloc;
    int w = dir ? (L - 1 - s) : s;
    float v = dbl[((size_t)b * L + w) * 48 + 16 + half * 16 + n];
    if (half == 0) Bsh[tloc][n] = v; else Csh[tloc][n] = v;
  }
  float h[16];
  size_t ho = (((size_t)c * B + b) * 256 + e) * 16;
#pragma unroll
  for (int n = 0; n < 16; n++) h[n] = h0[ho + n];
  float Dv = dskip[e];
  __syncthreads();
  for (int tl = 0; tl < LC; tl++) {
    int s = c * LC + tl;
    int w = dir ? (L - 1 - s) : s;
    size_t base = ((size_t)b * L + w) * 256 + e;
    float d = dtg[base];
    float xv = xc[base];
    float zv = xz[((size_t)b * L + w) * 512 + 256 + e];
    float du = d * xv;
    float y = 0.f;
#pragma unroll
    for (int n = 0; n < 16; n++) {
      float dA = __expf(d * Aa[n]);
      h[n] = fmaf(dA, h[n], du * Bsh[tl][n]);
      y = fmaf(h[n], Csh[tl][n], y);
    }
    y = fmaf(xv, Dv, y);
    dtg[base] = y * (zv * sigmoidf_(zv));   // in-place: dt[base] already consumed
  }
}

// ---------------- mean pool (partial sums + atomics) and classifier head ----------------
__global__ void pool_partial(const float* __restrict__ seq, float* __restrict__ pooled) {
  int b = blockIdx.x >> 4;
  int tc = blockIdx.x & 15;
  int e = threadIdx.x;
  float s = 0.f;
  for (int tl = 0; tl < LC; tl++) {
    int t = tc * LC + tl;
    s += seq[((size_t)b * L + t) * 256 + e];
  }
  atomicAdd(&pooled[b * 256 + e], s * (1.f / L));
}

__global__ void classify(const float* __restrict__ pooled, const float* __restrict__ cw,
                         const float* __restrict__ cb, float* __restrict__ out) {
  int tid = threadIdx.x;
  if (tid < B * NC) {
    int b = tid / NC, cidx = tid % NC;
    float acc = cb[cidx];
    for (int k = 0; k < DM; k++) acc = fmaf(pooled[b * 256 + k], cw[cidx * 256 + k], acc);
    out[b * NC + cidx] = acc;
  }
}

extern "C" void kernel_launch(void* const* d_in, const int* in_sizes, int n_in,
                              void* d_out, int out_size, void* d_ws, size_t ws_size,
                              hipStream_t stream) {
  const float* x      = (const float*)d_in[0];
  const float* pw     = (const float*)d_in[1];
  const float* pb     = (const float*)d_in[2];
  const float* W_in   = (const float*)d_in[3];
  const float* conv_w = (const float*)d_in[4];
  const float* conv_b = (const float*)d_in[5];
  const float* W_x    = (const float*)d_in[6];
  const float* W_dt   = (const float*)d_in[7];
  const float* b_dt   = (const float*)d_in[8];
  const float* A_log  = (const float*)d_in[9];
  const float* D_skip = (const float*)d_in[10];
  const float* W_out  = (const float*)d_in[11];
  const float* cls_w  = (const float*)d_in[12];
  const float* cls_b  = (const float*)d_in[13];
  float* out = (float*)d_out;

  char* p = (char*)d_ws;
  auto alloc = [&](size_t bytes) {
    float* r = (float*)p;
    p += (bytes + 255) & ~(size_t)255;
    return r;
  };
  float* seqA   = alloc((size_t)M * 256 * 4);
  float* seqB   = alloc((size_t)M * 256 * 4);
  float* xz     = alloc((size_t)M * 512 * 4);
  float* xc     = alloc((size_t)M * 256 * 4);
  float* dbl    = alloc((size_t)M * 48 * 4);
  float* dtg    = alloc((size_t)M * 256 * 4);
  float* hfin   = alloc((size_t)NCH * B * 256 * 16 * 4);
  float* sumdt  = alloc((size_t)NCH * B * 256 * 4);
  float* h0     = alloc((size_t)NCH * B * 256 * 16 * 4);
  float* pooled = alloc((size_t)B * 256 * 4);

  patch_embed<<<M, 256, 0, stream>>>(x, pw, pb, seqA);

  float* bufs[3] = {seqA, seqB, seqA};
  for (int i = 0; i < NB; i++) {
    const float* sin = bufs[i];
    float* sout = bufs[i + 1];
    for (int d = 0; d < 2; d++) {
      int id = i * 2 + d;
      gemm_f32<<<dim3(4, M / 128), 256, 0, stream>>>(
          sin, W_in + (size_t)id * 256 * 512, xz, 512, 256, 0);
      conv_silu<<<M, 256, 0, stream>>>(
          xz, conv_w + id * 256 * 4, conv_b + id * 256, xc, d);
      gemm_f32<<<dim3(1, M / 128), 256, 0, stream>>>(
          xc, W_x + (size_t)id * 256 * 48, dbl, 48, 256, 0);
      dt_softplus<<<M, 256, 0, stream>>>(
          dbl, W_dt + id * 16 * 256, b_dt + id * 256, dtg);
      scan_passA<<<B * NCH, 256, 0, stream>>>(
          dtg, xc, dbl, A_log + id * 256 * 16, hfin, sumdt, d);
      scan_passB<<<B * 256 * 16 / 256, 256, 0, stream>>>(
          hfin, sumdt, A_log + id * 256 * 16, h0);
      scan_passC<<<B * NCH, 256, 0, stream>>>(
          dtg, xc, dbl, xz, A_log + id * 256 * 16, D_skip + id * 256, h0, d);
      gemm_f32<<<dim3(2, M / 128), 256, 0, stream>>>(
          dtg, W_out + (size_t)id * 256 * 256, sout, 256, 256, d == 0 ? 0 : 1);
    }
  }
  hipMemsetAsync(pooled, 0, B * 256 * 4, stream);
  pool_partial<<<B * 16, 256, 0, stream>>>(bufs[NB], pooled);
  classify<<<1, 128, 0, stream>>>(pooled, cls_w, cls_b, out);
}

// Round 2
// 871.861 us; speedup vs baseline: 1.6378x; 1.6378x over previous
//
#include <hip/hip_runtime.h>
#include <math.h>

// Problem constants
constexpr int B = 8;
constexpr int H = 16;
constexpr int W = 4096;
constexpr int L = 2048;      // GW
constexpr int DM = 256;
constexpr int DI = 256;
constexpr int NSTATE = 16;
constexpr int NB = 2;
constexpr int NC = 10;
constexpr int LC = 32;       // scan chunk length
constexpr int NCH = L / LC;  // 64 chunks
constexpr int M = B * L;     // 16384 rows for all GEMMs

__device__ __forceinline__ float sigmoidf_(float v) { return 1.f / (1.f + __expf(-v)); }

// ---------------- patch embed: seq[b, t, gh*32+e] = conv2x2(x) + bias ----------------
__global__ void patch_embed(const float* __restrict__ x, const float* __restrict__ pw,
                            const float* __restrict__ pb, float* __restrict__ seq) {
  int idx = blockIdx.x * 256 + threadIdx.x;   // B*L*DM total
  int m = idx & 255;
  int bt = idx >> 8;
  int t = bt & (L - 1);
  int b = bt >> 11;
  int gh = m >> 5, e = m & 31;
  const float* xp = x + ((size_t)b * H + gh * 2) * W + t * 2;
  float acc = pb[e];
  acc = fmaf(xp[0],     pw[e * 4 + 0], acc);
  acc = fmaf(xp[1],     pw[e * 4 + 1], acc);
  acc = fmaf(xp[W],     pw[e * 4 + 2], acc);
  acc = fmaf(xp[W + 1], pw[e * 4 + 3], acc);
  seq[idx] = acc;
}

// ---------------- fp32 GEMM: C[M,N] = Acat[M,K] @ Bg[K,N], 128x128x16 tiles ----------------
// A is split into two row-major planes A0 (k < kSplit) and A1 (k >= kSplit), each with
// row stride lda. Per-z batching via Astride/Bstride/Cstride.
__global__ __launch_bounds__(256) void gemm_f32(
    const float* __restrict__ A0, const float* __restrict__ A1, int lda, int kSplit,
    size_t Astride, const float* __restrict__ Bg, size_t Bstride,
    float* __restrict__ C, size_t Cstride, int N, int K) {
  int z = blockIdx.z;
  A0 += (size_t)z * Astride;
  A1 += (size_t)z * Astride;
  Bg += (size_t)z * Bstride;
  C  += (size_t)z * Cstride;
  __shared__ float As[16][132];   // transposed A tile, padded
  __shared__ float Bs[16][128];
  int tid = threadIdx.x;
  int tx = tid & 15, ty = tid >> 4;
  int m0 = blockIdx.y * 128, n0 = blockIdx.x * 128;
  float acc[8][8] = {};
  for (int k0 = 0; k0 < K; k0 += 16) {
    const float* Asel = (k0 < kSplit) ? A0 : A1;
    int kof = (k0 < kSplit) ? k0 : (k0 - kSplit);
#pragma unroll
    for (int rep = 0; rep < 2; rep++) {
      int mm = (tid >> 2) + rep * 64;
      int kg = (tid & 3) * 4;
      float4 v = *(const float4*)&Asel[(size_t)(m0 + mm) * lda + kof + kg];
      As[kg + 0][mm] = v.x; As[kg + 1][mm] = v.y;
      As[kg + 2][mm] = v.z; As[kg + 3][mm] = v.w;
    }
#pragma unroll
    for (int rep = 0; rep < 2; rep++) {
      int kk = (tid >> 5) + rep * 8;
      int nn = (tid & 31) * 4;
      int n = n0 + nn;
      float4 v = make_float4(0.f, 0.f, 0.f, 0.f);
      const float* src = Bg + (size_t)(k0 + kk) * N;
      if (n + 3 < N) {
        v = *(const float4*)(src + n);
      } else if (n < N) {
        v.x = src[n];
        if (n + 1 < N) v.y = src[n + 1];
        if (n + 2 < N) v.z = src[n + 2];
      }
      *(float4*)&Bs[kk][nn] = v;
    }
    __syncthreads();
#pragma unroll
    for (int k = 0; k < 16; k++) {
      float a[8], bv[8];
      *(float4*)&a[0] = *(const float4*)&As[k][ty * 4];
      *(float4*)&a[4] = *(const float4*)&As[k][64 + ty * 4];
      *(float4*)&bv[0] = *(const float4*)&Bs[k][tx * 4];
      *(float4*)&bv[4] = *(const float4*)&Bs[k][64 + tx * 4];
#pragma unroll
      for (int i = 0; i < 8; i++)
#pragma unroll
        for (int j = 0; j < 8; j++)
          acc[i][j] = fmaf(a[i], bv[j], acc[i][j]);
    }
    __syncthreads();
  }
#pragma unroll
  for (int i = 0; i < 8; i++) {
    int m = m0 + ty * 4 + (i & 3) + (i >> 2) * 64;
    float* crow = C + (size_t)m * N;
#pragma unroll
    for (int jh = 0; jh < 2; jh++) {
      int n = n0 + tx * 4 + jh * 64;
      if (n + 3 < N) {
        float4 v;
        v.x = acc[i][jh * 4 + 0]; v.y = acc[i][jh * 4 + 1];
        v.z = acc[i][jh * 4 + 2]; v.w = acc[i][jh * 4 + 3];
        *(float4*)&crow[n] = v;
      } else {
        for (int q = 0; q < 4; q++) {
          if (n + q < N) crow[n + q] = acc[i][jh * 4 + q];
        }
      }
    }
  }
}

// ---------------- depthwise conv + silu, z-batched (z = dir) ----------------
// xi lives in the first 256 columns of xz plane (row stride 512)
__global__ void conv_silu(const float* __restrict__ xz, const float* __restrict__ cw,
                          const float* __restrict__ cb, float* __restrict__ xc) {
  int z = blockIdx.y;
  int idx = blockIdx.x * 256 + threadIdx.x;   // B*L*DI
  int e = idx & 255;
  int bt = idx >> 8;
  int t = bt & (L - 1);
  int b = bt >> 11;
  const float* cwz = cw + z * 1024;
  float w0 = cwz[e * 4 + 0], w1 = cwz[e * 4 + 1], w2 = cwz[e * 4 + 2], w3 = cwz[e * 4 + 3];
  float acc = cb[z * 256 + e];
  const float* base = xz + (size_t)z * M * 512 + (size_t)b * L * 512 + e;
  if (z == 0) {
    if (t >= 3) acc = fmaf(w0, base[(size_t)(t - 3) * 512], acc);
    if (t >= 2) acc = fmaf(w1, base[(size_t)(t - 2) * 512], acc);
    if (t >= 1) acc = fmaf(w2, base[(size_t)(t - 1) * 512], acc);
    acc = fmaf(w3, base[(size_t)t * 512], acc);
  } else {
    if (t + 3 < L) acc = fmaf(w0, base[(size_t)(t + 3) * 512], acc);
    if (t + 2 < L) acc = fmaf(w1, base[(size_t)(t + 2) * 512], acc);
    if (t + 1 < L) acc = fmaf(w2, base[(size_t)(t + 1) * 512], acc);
    acc = fmaf(w3, base[(size_t)t * 512], acc);
  }
  xc[(size_t)z * M * 256 + idx] = acc * sigmoidf_(acc);
}

// ---------------- dt = softplus(dt_raw @ W_dt + b_dt), K=16, z-batched ----------------
__global__ void dt_softplus(const float* __restrict__ dbl, const float* __restrict__ wdt,
                            const float* __restrict__ bdt, float* __restrict__ dt) {
  int z = blockIdx.y;
  int bt = blockIdx.x;
  int e = threadIdx.x;
  __shared__ float r[16];
  if (e < 16) r[e] = dbl[(size_t)z * M * 48 + (size_t)bt * 48 + e];
  __syncthreads();
  const float* wz = wdt + z * 4096;
  float acc = bdt[z * 256 + e];
#pragma unroll
  for (int k = 0; k < 16; k++) acc = fmaf(r[k], wz[k * 256 + e], acc);
  float sp = (acc > 20.f) ? acc : log1pf(expf(acc));
  dt[(size_t)z * M * 256 + (size_t)bt * 256 + e] = sp;
}

// ---------------- scan pass A: per-chunk local h recurrence (h0=0), chunk dt-sums ----------------
// block = (z, b, c); 2*B*NCH blocks
__global__ __launch_bounds__(256) void scan_passA(
    const float* __restrict__ dt, const float* __restrict__ xc,
    const float* __restrict__ dbl, const float* __restrict__ alog,
    float* __restrict__ hfin, float* __restrict__ sumdt) {
  int bc = blockIdx.x;
  int c = bc & (NCH - 1);
  int b = (bc >> 6) & 7;
  int z = bc >> 9;
  int e = threadIdx.x;
  const float* dt_p = dt + (size_t)z * M * 256;
  const float* xc_p = xc + (size_t)z * M * 256;
  const float* dbl_p = dbl + (size_t)z * M * 48;
  const float* al = alog + z * 4096;
  __shared__ float Bsh[LC][NSTATE];
  float Aa[16];
#pragma unroll
  for (int n = 0; n < 16; n++) Aa[n] = -__expf(al[e * 16 + n]);
  {
    int i0 = e * 2;                 // 512 elems, 2 per thread (float2)
    int row = i0 >> 4, col = i0 & 15;
    int s = c * LC + row;
    int w = z ? (L - 1 - s) : s;
    const float* src = dbl_p + ((size_t)b * L + w) * 48 + 16 + col;
    float2 v = *(const float2*)src;
    Bsh[row][col] = v.x; Bsh[row][col + 1] = v.y;
  }
  __syncthreads();
  float h[16];
#pragma unroll
  for (int n = 0; n < 16; n++) h[n] = 0.f;
  float sdt = 0.f;
  for (int tl = 0; tl < LC; tl++) {
    int s = c * LC + tl;
    int w = z ? (L - 1 - s) : s;
    size_t base = ((size_t)b * L + w) * 256 + e;
    float d = dt_p[base];
    float xv = xc_p[base];
    sdt += d;
    float du = d * xv;
#pragma unroll
    for (int n = 0; n < 16; n++) {
      float dA = __expf(d * Aa[n]);
      h[n] = fmaf(dA, h[n], du * Bsh[tl][n]);
    }
  }
  size_t o = ((((size_t)z * NCH + c) * B + b) * 256 + e) * 16;
#pragma unroll
  for (int n = 0; n < 16; n++) hfin[o + n] = h[n];
  sumdt[(((size_t)z * NCH + c) * B + b) * 256 + e] = sdt;
}

// ---------------- scan pass B: sequential chunk combine (tiny) ----------------
__global__ void scan_passB(const float* __restrict__ hfin, const float* __restrict__ sumdt,
                           const float* __restrict__ alog, float* __restrict__ h0) {
  int idx = blockIdx.x * 256 + threadIdx.x;   // 2*B*DI*NSTATE = 65536
  int n = idx & 15;
  int e = (idx >> 4) & 255;
  int b = (idx >> 12) & 7;
  int z = idx >> 15;
  float Aa = -__expf(alog[z * 4096 + e * 16 + n]);
  float h = 0.f;
  for (int c = 0; c < NCH; c++) {
    size_t o = ((((size_t)z * NCH + c) * B + b) * 256 + e) * 16 + n;
    h0[o] = h;
    float P = __expf(Aa * sumdt[(((size_t)z * NCH + c) * B + b) * 256 + e]);
    h = fmaf(P, h, hfin[o]);
  }
}

// ---------------- scan pass C: replay with h0, fuse +xc*D and *silu(z-gate); in-place over dt ----------------
__global__ __launch_bounds__(256) void scan_passC(
    float* __restrict__ dtg, const float* __restrict__ xc,
    const float* __restrict__ dbl, const float* __restrict__ xz,
    const float* __restrict__ alog, const float* __restrict__ dskip,
    const float* __restrict__ h0) {
  int bc = blockIdx.x;
  int c = bc & (NCH - 1);
  int b = (bc >> 6) & 7;
  int z = bc >> 9;
  int e = threadIdx.x;
  float* dt_p = dtg + (size_t)z * M * 256;
  const float* xc_p = xc + (size_t)z * M * 256;
  const float* dbl_p = dbl + (size_t)z * M * 48;
  const float* xz_p = xz + (size_t)z * M * 512;
  const float* al = alog + z * 4096;
  __shared__ float Ssh[LC][32];   // cols [0:16)=B, [16:32)=C of this chunk
  float Aa[16];
#pragma unroll
  for (int n = 0; n < 16; n++) Aa[n] = -__expf(al[e * 16 + n]);
  {
    int row = e >> 3;               // 32 rows x 8 float4 = 256 loads, 1 per thread
    int colg = (e & 7) * 4;
    int s = c * LC + row;
    int w = z ? (L - 1 - s) : s;
    const float* src = dbl_p + ((size_t)b * L + w) * 48 + 16 + colg;
    float4 v = *(const float4*)src;
    Ssh[row][colg + 0] = v.x; Ssh[row][colg + 1] = v.y;
    Ssh[row][colg + 2] = v.z; Ssh[row][colg + 3] = v.w;
  }
  float h[16];
  size_t ho = ((((size_t)z * NCH + c) * B + b) * 256 + e) * 16;
#pragma unroll
  for (int n = 0; n < 16; n++) h[n] = h0[ho + n];
  float Dv = dskip[z * 256 + e];
  __syncthreads();
  for (int tl = 0; tl < LC; tl++) {
    int s = c * LC + tl;
    int w = z ? (L - 1 - s) : s;
    size_t base = ((size_t)b * L + w) * 256 + e;
    float d = dt_p[base];
    float xv = xc_p[base];
    float zv = xz_p[((size_t)b * L + w) * 512 + 256 + e];
    float du = d * xv;
    float y = 0.f;
#pragma unroll
    for (int n = 0; n < 16; n++) {
      float dA = __expf(d * Aa[n]);
      h[n] = fmaf(dA, h[n], du * Ssh[tl][n]);
      y = fmaf(h[n], Ssh[tl][16 + n], y);
    }
    y = fmaf(xv, Dv, y);
    dt_p[base] = y * (zv * sigmoidf_(zv));   // in-place: dt[base] already consumed
  }
}

// ---------------- mean pool (partial sums + atomics) and classifier head ----------------
__global__ void pool_partial(const float* __restrict__ seq, float* __restrict__ pooled) {
  int b = blockIdx.x >> 4;
  int tc = blockIdx.x & 15;
  int e = threadIdx.x;
  float s = 0.f;
  for (int tl = 0; tl < 128; tl++) {
    int t = tc * 128 + tl;
    s += seq[((size_t)b * L + t) * 256 + e];
  }
  atomicAdd(&pooled[b * 256 + e], s * (1.f / L));
}

__global__ void classify(const float* __restrict__ pooled, const float* __restrict__ cw,
                         const float* __restrict__ cb, float* __restrict__ out) {
  int tid = threadIdx.x;
  if (tid < B * NC) {
    int b = tid / NC, cidx = tid % NC;
    float acc = cb[cidx];
    for (int k = 0; k < DM; k++) acc = fmaf(pooled[b * 256 + k], cw[cidx * 256 + k], acc);
    out[b * NC + cidx] = acc;
  }
}

extern "C" void kernel_launch(void* const* d_in, const int* in_sizes, int n_in,
                              void* d_out, int out_size, void* d_ws, size_t ws_size,
                              hipStream_t stream) {
  const float* x      = (const float*)d_in[0];
  const float* pw     = (const float*)d_in[1];
  const float* pb     = (const float*)d_in[2];
  const float* W_in   = (const float*)d_in[3];
  const float* conv_w = (const float*)d_in[4];
  const float* conv_b = (const float*)d_in[5];
  const float* W_x    = (const float*)d_in[6];
  const float* W_dt   = (const float*)d_in[7];
  const float* b_dt   = (const float*)d_in[8];
  const float* A_log  = (const float*)d_in[9];
  const float* D_skip = (const float*)d_in[10];
  const float* W_out  = (const float*)d_in[11];
  const float* cls_w  = (const float*)d_in[12];
  const float* cls_b  = (const float*)d_in[13];
  float* out = (float*)d_out;

  char* p = (char*)d_ws;
  auto alloc = [&](size_t bytes) {
    float* r = (float*)p;
    p += (bytes + 255) & ~(size_t)255;
    return r;
  };
  float* seqA   = alloc((size_t)M * 256 * 4);
  float* seqB   = alloc((size_t)M * 256 * 4);
  float* xz     = alloc((size_t)2 * M * 512 * 4);            // per-dir planes
  float* xc     = alloc((size_t)2 * M * 256 * 4);
  float* dbl    = alloc((size_t)2 * M * 48 * 4);
  float* dtg    = alloc((size_t)2 * M * 256 * 4);            // dt, then gated y in-place
  float* hfin   = alloc((size_t)2 * NCH * B * 256 * 16 * 4);
  float* sumdt  = alloc((size_t)2 * NCH * B * 256 * 4);
  float* h0     = alloc((size_t)2 * NCH * B * 256 * 16 * 4);
  float* pooled = alloc((size_t)B * 256 * 4);

  patch_embed<<<M, 256, 0, stream>>>(x, pw, pb, seqA);

  float* bufs[3] = {seqA, seqB, seqA};
  for (int i = 0; i < NB; i++) {
    const float* sin = bufs[i];
    float* sout = bufs[i + 1];
    // xz[z] = sin @ W_in[i,z]   (A shared across z)
    gemm_f32<<<dim3(4, M / 128, 2), 256, 0, stream>>>(
        sin, sin, 256, 256, 0,
        W_in + (size_t)i * 2 * 256 * 512, (size_t)256 * 512,
        xz, (size_t)M * 512, 512, 256);
    conv_silu<<<dim3(M, 2), 256, 0, stream>>>(
        xz, conv_w + i * 2 * 1024, conv_b + i * 2 * 256, xc);
    // dbl[z] = xc[z] @ W_x[i,z]
    gemm_f32<<<dim3(1, M / 128, 2), 256, 0, stream>>>(
        xc, xc, 256, 256, (size_t)M * 256,
        W_x + (size_t)i * 2 * 256 * 48, (size_t)256 * 48,
        dbl, (size_t)M * 48, 48, 256);
    dt_softplus<<<dim3(M, 2), 256, 0, stream>>>(
        dbl, W_dt + i * 2 * 4096, b_dt + i * 2 * 256, dtg);
    scan_passA<<<2 * B * NCH, 256, 0, stream>>>(
        dtg, xc, dbl, A_log + i * 2 * 4096, hfin, sumdt);
    scan_passB<<<2 * B * 256 * 16 / 256, 256, 0, stream>>>(
        hfin, sumdt, A_log + i * 2 * 4096, h0);
    scan_passC<<<2 * B * NCH, 256, 0, stream>>>(
        dtg, xc, dbl, xz, A_log + i * 2 * 4096, D_skip + i * 2 * 256, h0);
    // sout = [y_fwd | y_rev] @ [W_out[i,0]; W_out[i,1]]  (K=512 cat GEMM)
    gemm_f32<<<dim3(2, M / 128, 1), 256, 0, stream>>>(
        dtg, dtg + (size_t)M * 256, 256, 256, 0,
        W_out + (size_t)i * 2 * 256 * 256, 0,
        sout, 0, 256, 512);
  }
  hipMemsetAsync(pooled, 0, B * 256 * 4, stream);
  pool_partial<<<B * 16, 256, 0, stream>>>(bufs[NB], pooled);
  classify<<<1, 128, 0, stream>>>(pooled, cls_w, cls_b, out);
}

// Round 3
// 630.338 us; speedup vs baseline: 2.2654x; 1.3832x over previous
//
#include <hip/hip_runtime.h>
#include <math.h>

// Problem constants
constexpr int B = 8;
constexpr int H = 16;
constexpr int W = 4096;
constexpr int L = 2048;      // GW
constexpr int NSTATE = 16;
constexpr int NB = 2;
constexpr int NC = 10;
constexpr int LC = 32;       // scan chunk length
constexpr int NCH = L / LC;  // 64 chunks
constexpr int M = B * L;     // 16384 rows for all GEMMs

typedef unsigned short u16;
typedef __attribute__((ext_vector_type(8))) short bf16x8;
typedef __attribute__((ext_vector_type(4))) float f32x4;

__device__ __forceinline__ float sigmoidf_(float v) { return 1.f / (1.f + __expf(-v)); }

__device__ __forceinline__ u16 bf16_of(float x) {   // round-to-nearest-even bf16 bits
  unsigned u = __float_as_uint(x);
  u += 0x7FFF + ((u >> 16) & 1);
  return (u16)(u >> 16);
}
__device__ __forceinline__ float bf16_to_f(u16 h) { return __uint_as_float((unsigned)h << 16); }

// ---------------- weight prep: transpose + hi/lo split (runs once per launch, tiny) ----------------
// winT[id][n][k]  (id = i*2+z, N=512, K=256) from W_in[id][k][n]
// woutT[i][n][z*256+k] (N=256, Kcat=512)     from W_out[i*2+z][k][n]
__global__ void prep_weights(const float* __restrict__ Win, const float* __restrict__ Wout,
                             u16* __restrict__ winT_h, u16* __restrict__ winT_l,
                             u16* __restrict__ woutT_h, u16* __restrict__ woutT_l) {
  int idx = blockIdx.x * 256 + threadIdx.x;   // 786432 total
  if (idx < 524288) {
    int id = idx >> 17;
    int rem = idx & 131071;
    int n = rem >> 8, k = rem & 255;
    float v = Win[(size_t)id * 131072 + (size_t)k * 512 + n];
    u16 hh = bf16_of(v);
    winT_h[idx] = hh;
    winT_l[idx] = bf16_of(v - bf16_to_f(hh));
  } else {
    int j = idx - 524288;
    int i = j >> 17;
    int rem = j & 131071;
    int n = rem >> 9, kc = rem & 511;
    int z = kc >> 8, k = kc & 255;
    float v = Wout[(((size_t)(i * 2 + z) * 256) + k) * 256 + n];
    u16 hh = bf16_of(v);
    woutT_h[j] = hh;
    woutT_l[j] = bf16_of(v - bf16_to_f(hh));
  }
}

// ---------------- patch embed -> bf16 hi/lo planes ----------------
__global__ void patch_embed(const float* __restrict__ x, const float* __restrict__ pw,
                            const float* __restrict__ pb, u16* __restrict__ sh,
                            u16* __restrict__ sl) {
  int idx = blockIdx.x * 256 + threadIdx.x;   // B*L*DM
  int m = idx & 255;
  int bt = idx >> 8;
  int t = bt & (L - 1);
  int b = bt >> 11;
  int gh = m >> 5, e = m & 31;
  const float* xp = x + ((size_t)b * H + gh * 2) * W + t * 2;
  float acc = pb[e];
  acc = fmaf(xp[0],     pw[e * 4 + 0], acc);
  acc = fmaf(xp[1],     pw[e * 4 + 1], acc);
  acc = fmaf(xp[W],     pw[e * 4 + 2], acc);
  acc = fmaf(xp[W + 1], pw[e * 4 + 3], acc);
  u16 hh = bf16_of(acc);
  sh[idx] = hh;
  sl[idx] = bf16_of(acc - bf16_to_f(hh));
}

// ---------------- MFMA GEMM, fp32-accurate via bf16 hi/lo 3-term ----------------
// C[M][N] = A[M][K] * Bt^T, A given as hi/lo bf16 planes (two K-halves Ah0/Ah1 split at
// kSplit, row stride lda in u16 elems), Bt as [N][K] hi/lo planes (row stride K).
// Outputs: fp32 C (if non-null) and/or bf16 hi/lo planes Ch/Cl (if non-null), ldc cols.
__global__ __launch_bounds__(256) void gemm_mfma(
    const u16* __restrict__ Ah0, const u16* __restrict__ Al0,
    const u16* __restrict__ Ah1, const u16* __restrict__ Al1,
    int lda, int kSplit,
    const u16* __restrict__ BTh, const u16* __restrict__ BTl, size_t BzStride,
    float* __restrict__ C, size_t CzStride, int ldc,
    u16* __restrict__ Ch, u16* __restrict__ Cl, int K) {
  int z = blockIdx.z;
  BTh += (size_t)z * BzStride;
  BTl += (size_t)z * BzStride;
  if (C) C += (size_t)z * CzStride;
  __shared__ __align__(16) u16 As_h[4096], As_l[4096], Bs_h[4096], Bs_l[4096];
  int t = threadIdx.x;
  int m0 = blockIdx.y * 128, n0 = blockIdx.x * 128;
  // staging map: thread t -> row = t>>1, phys groups {p0, p0+1}, p0 = (t&1)*2
  int row = t >> 1;
  int p0 = (t & 1) * 2;
  int sw = (row >> 1) & 3;
  int kg0 = p0 ^ sw;                 // logical k-group of phys group p0 (kg of p0+1 is kg0^1)
  int lidx0 = row * 32 + p0 * 8;     // u16 index of phys chunk p0
  size_t aoffs = (size_t)(m0 + row) * lda;
  size_t boffs = (size_t)(n0 + row) * K;
  int lane = t & 63;
  int wave = t >> 6;
  int wm = (wave >> 1) * 64, wn = (wave & 1) * 64;
  int lm = lane & 15, q = lane >> 4;
  f32x4 zero = {0.f, 0.f, 0.f, 0.f};
  f32x4 acc[4][4];
#pragma unroll
  for (int mt = 0; mt < 4; mt++)
#pragma unroll
    for (int nt = 0; nt < 4; nt++) acc[mt][nt] = zero;

  for (int k0 = 0; k0 < K; k0 += 32) {
    const u16* pAh = Ah0;
    const u16* pAl = Al0;
    int kof = k0;
    if (k0 >= kSplit) { pAh = Ah1; pAl = Al1; kof = k0 - kSplit; }
    uint4 a_h0 = *(const uint4*)(pAh + aoffs + kof + kg0 * 8);
    uint4 a_h1 = *(const uint4*)(pAh + aoffs + kof + (kg0 ^ 1) * 8);
    uint4 a_l0 = *(const uint4*)(pAl + aoffs + kof + kg0 * 8);
    uint4 a_l1 = *(const uint4*)(pAl + aoffs + kof + (kg0 ^ 1) * 8);
    uint4 b_h0 = *(const uint4*)(BTh + boffs + k0 + kg0 * 8);
    uint4 b_h1 = *(const uint4*)(BTh + boffs + k0 + (kg0 ^ 1) * 8);
    uint4 b_l0 = *(const uint4*)(BTl + boffs + k0 + kg0 * 8);
    uint4 b_l1 = *(const uint4*)(BTl + boffs + k0 + (kg0 ^ 1) * 8);
    __syncthreads();
    *(uint4*)&As_h[lidx0] = a_h0; *(uint4*)&As_h[lidx0 + 8] = a_h1;
    *(uint4*)&As_l[lidx0] = a_l0; *(uint4*)&As_l[lidx0 + 8] = a_l1;
    *(uint4*)&Bs_h[lidx0] = b_h0; *(uint4*)&Bs_h[lidx0 + 8] = b_h1;
    *(uint4*)&Bs_l[lidx0] = b_l0; *(uint4*)&Bs_l[lidx0 + 8] = b_l1;
    __syncthreads();
    bf16x8 ah[4], al[4], bh[4], bl[4];
#pragma unroll
    for (int i4 = 0; i4 < 4; i4++) {
      int ra = wm + i4 * 16 + lm;
      int ia = ra * 32 + (q ^ ((ra >> 1) & 3)) * 8;
      ah[i4] = *(const bf16x8*)&As_h[ia];
      al[i4] = *(const bf16x8*)&As_l[ia];
      int rb = wn + i4 * 16 + lm;
      int ib = rb * 32 + (q ^ ((rb >> 1) & 3)) * 8;
      bh[i4] = *(const bf16x8*)&Bs_h[ib];
      bl[i4] = *(const bf16x8*)&Bs_l[ib];
    }
#pragma unroll
    for (int mt = 0; mt < 4; mt++)
#pragma unroll
      for (int nt = 0; nt < 4; nt++) {
        f32x4 c = acc[mt][nt];
        c = __builtin_amdgcn_mfma_f32_16x16x32_bf16(ah[mt], bl[nt], c, 0, 0, 0);
        c = __builtin_amdgcn_mfma_f32_16x16x32_bf16(al[mt], bh[nt], c, 0, 0, 0);
        c = __builtin_amdgcn_mfma_f32_16x16x32_bf16(ah[mt], bh[nt], c, 0, 0, 0);
        acc[mt][nt] = c;
      }
  }
  // epilogue: C/D layout col = lane&15, row = q*4 + r
#pragma unroll
  for (int mt = 0; mt < 4; mt++) {
#pragma unroll
    for (int r = 0; r < 4; r++) {
      int gm = m0 + wm + mt * 16 + q * 4 + r;
      size_t rowoff = (size_t)gm * ldc + n0 + wn;
#pragma unroll
      for (int nt = 0; nt < 4; nt++) {
        float v = acc[mt][nt][r];
        int cn = nt * 16 + lm;
        if (C) C[rowoff + cn] = v;
        if (Ch) {
          u16 hh = bf16_of(v);
          Ch[rowoff + cn] = hh;
          Cl[rowoff + cn] = bf16_of(v - bf16_to_f(hh));
        }
      }
    }
  }
}

// ---------------- fp32 vector GEMM (kept for W_x, N=48) ----------------
__global__ __launch_bounds__(256) void gemm_f32(
    const float* __restrict__ A0, const float* __restrict__ A1, int lda, int kSplit,
    size_t Astride, const float* __restrict__ Bg, size_t Bstride,
    float* __restrict__ C, size_t Cstride, int N, int K) {
  int z = blockIdx.z;
  A0 += (size_t)z * Astride;
  A1 += (size_t)z * Astride;
  Bg += (size_t)z * Bstride;
  C  += (size_t)z * Cstride;
  __shared__ float As[16][132];
  __shared__ float Bs[16][128];
  int tid = threadIdx.x;
  int tx = tid & 15, ty = tid >> 4;
  int m0 = blockIdx.y * 128, n0 = blockIdx.x * 128;
  float acc[8][8] = {};
  for (int k0 = 0; k0 < K; k0 += 16) {
    const float* Asel = (k0 < kSplit) ? A0 : A1;
    int kof = (k0 < kSplit) ? k0 : (k0 - kSplit);
#pragma unroll
    for (int rep = 0; rep < 2; rep++) {
      int mm = (tid >> 2) + rep * 64;
      int kg = (tid & 3) * 4;
      float4 v = *(const float4*)&Asel[(size_t)(m0 + mm) * lda + kof + kg];
      As[kg + 0][mm] = v.x; As[kg + 1][mm] = v.y;
      As[kg + 2][mm] = v.z; As[kg + 3][mm] = v.w;
    }
#pragma unroll
    for (int rep = 0; rep < 2; rep++) {
      int kk = (tid >> 5) + rep * 8;
      int nn = (tid & 31) * 4;
      int n = n0 + nn;
      float4 v = make_float4(0.f, 0.f, 0.f, 0.f);
      const float* src = Bg + (size_t)(k0 + kk) * N;
      if (n + 3 < N) {
        v = *(const float4*)(src + n);
      } else if (n < N) {
        v.x = src[n];
        if (n + 1 < N) v.y = src[n + 1];
        if (n + 2 < N) v.z = src[n + 2];
      }
      *(float4*)&Bs[kk][nn] = v;
    }
    __syncthreads();
#pragma unroll
    for (int k = 0; k < 16; k++) {
      float a[8], bv[8];
      *(float4*)&a[0] = *(const float4*)&As[k][ty * 4];
      *(float4*)&a[4] = *(const float4*)&As[k][64 + ty * 4];
      *(float4*)&bv[0] = *(const float4*)&Bs[k][tx * 4];
      *(float4*)&bv[4] = *(const float4*)&Bs[k][64 + tx * 4];
#pragma unroll
      for (int i = 0; i < 8; i++)
#pragma unroll
        for (int j = 0; j < 8; j++)
          acc[i][j] = fmaf(a[i], bv[j], acc[i][j]);
    }
    __syncthreads();
  }
#pragma unroll
  for (int i = 0; i < 8; i++) {
    int m = m0 + ty * 4 + (i & 3) + (i >> 2) * 64;
    float* crow = C + (size_t)m * N;
#pragma unroll
    for (int jh = 0; jh < 2; jh++) {
      int n = n0 + tx * 4 + jh * 64;
      if (n + 3 < N) {
        float4 v;
        v.x = acc[i][jh * 4 + 0]; v.y = acc[i][jh * 4 + 1];
        v.z = acc[i][jh * 4 + 2]; v.w = acc[i][jh * 4 + 3];
        *(float4*)&crow[n] = v;
      } else {
        for (int q = 0; q < 4; q++)
          if (n + q < N) crow[n + q] = acc[i][jh * 4 + q];
      }
    }
  }
}

// ---------------- depthwise conv + silu, z-batched (z = dir) ----------------
__global__ void conv_silu(const float* __restrict__ xz, const float* __restrict__ cw,
                          const float* __restrict__ cb, float* __restrict__ xc) {
  int z = blockIdx.y;
  int idx = blockIdx.x * 256 + threadIdx.x;
  int e = idx & 255;
  int bt = idx >> 8;
  int t = bt & (L - 1);
  int b = bt >> 11;
  const float* cwz = cw + z * 1024;
  float w0 = cwz[e * 4 + 0], w1 = cwz[e * 4 + 1], w2 = cwz[e * 4 + 2], w3 = cwz[e * 4 + 3];
  float acc = cb[z * 256 + e];
  const float* base = xz + (size_t)z * M * 512 + (size_t)b * L * 512 + e;
  if (z == 0) {
    if (t >= 3) acc = fmaf(w0, base[(size_t)(t - 3) * 512], acc);
    if (t >= 2) acc = fmaf(w1, base[(size_t)(t - 2) * 512], acc);
    if (t >= 1) acc = fmaf(w2, base[(size_t)(t - 1) * 512], acc);
    acc = fmaf(w3, base[(size_t)t * 512], acc);
  } else {
    if (t + 3 < L) acc = fmaf(w0, base[(size_t)(t + 3) * 512], acc);
    if (t + 2 < L) acc = fmaf(w1, base[(size_t)(t + 2) * 512], acc);
    if (t + 1 < L) acc = fmaf(w2, base[(size_t)(t + 1) * 512], acc);
    acc = fmaf(w3, base[(size_t)t * 512], acc);
  }
  xc[(size_t)z * M * 256 + idx] = acc * sigmoidf_(acc);
}

// ---------------- dt = softplus(dt_raw @ W_dt + b_dt), K=16, z-batched ----------------
__global__ void dt_softplus(const float* __restrict__ dbl, const float* __restrict__ wdt,
                            const float* __restrict__ bdt, float* __restrict__ dt) {
  int z = blockIdx.y;
  int bt = blockIdx.x;
  int e = threadIdx.x;
  __shared__ float r[16];
  if (e < 16) r[e] = dbl[(size_t)z * M * 48 + (size_t)bt * 48 + e];
  __syncthreads();
  const float* wz = wdt + z * 4096;
  float acc = bdt[z * 256 + e];
#pragma unroll
  for (int k = 0; k < 16; k++) acc = fmaf(r[k], wz[k * 256 + e], acc);
  float sp = (acc > 20.f) ? acc : log1pf(expf(acc));
  dt[(size_t)z * M * 256 + (size_t)bt * 256 + e] = sp;
}

// ---------------- scan pass A ----------------
__global__ __launch_bounds__(256) void scan_passA(
    const float* __restrict__ dt, const float* __restrict__ xc,
    const float* __restrict__ dbl, const float* __restrict__ alog,
    float* __restrict__ hfin, float* __restrict__ sumdt) {
  int bc = blockIdx.x;
  int c = bc & (NCH - 1);
  int b = (bc >> 6) & 7;
  int z = bc >> 9;
  int e = threadIdx.x;
  const float* dt_p = dt + (size_t)z * M * 256;
  const float* xc_p = xc + (size_t)z * M * 256;
  const float* dbl_p = dbl + (size_t)z * M * 48;
  const float* al = alog + z * 4096;
  __shared__ float Bsh[LC][NSTATE];
  float Aa[16];
#pragma unroll
  for (int n = 0; n < 16; n++) Aa[n] = -__expf(al[e * 16 + n]);
  {
    int i0 = e * 2;
    int row = i0 >> 4, col = i0 & 15;
    int s = c * LC + row;
    int w = z ? (L - 1 - s) : s;
    const float* src = dbl_p + ((size_t)b * L + w) * 48 + 16 + col;
    float2 v = *(const float2*)src;
    Bsh[row][col] = v.x; Bsh[row][col + 1] = v.y;
  }
  __syncthreads();
  float h[16];
#pragma unroll
  for (int n = 0; n < 16; n++) h[n] = 0.f;
  float sdt = 0.f;
  for (int tl = 0; tl < LC; tl++) {
    int s = c * LC + tl;
    int w = z ? (L - 1 - s) : s;
    size_t base = ((size_t)b * L + w) * 256 + e;
    float d = dt_p[base];
    float xv = xc_p[base];
    sdt += d;
    float du = d * xv;
#pragma unroll
    for (int n = 0; n < 16; n++) {
      float dA = __expf(d * Aa[n]);
      h[n] = fmaf(dA, h[n], du * Bsh[tl][n]);
    }
  }
  size_t o = ((((size_t)z * NCH + c) * B + b) * 256 + e) * 16;
#pragma unroll
  for (int n = 0; n < 16; n++) hfin[o + n] = h[n];
  sumdt[(((size_t)z * NCH + c) * B + b) * 256 + e] = sdt;
}

// ---------------- scan pass B: chunk combine, h0 written in place of hfin ----------------
__global__ void scan_passB(float* __restrict__ hfin, const float* __restrict__ sumdt,
                           const float* __restrict__ alog) {
  int idx = blockIdx.x * 256 + threadIdx.x;   // 2*B*256*16 = 65536
  int n = idx & 15;
  int e = (idx >> 4) & 255;
  int b = (idx >> 12) & 7;
  int z = idx >> 15;
  float Aa = -__expf(alog[z * 4096 + e * 16 + n]);
  float h = 0.f;
  for (int c = 0; c < NCH; c++) {
    size_t o = ((((size_t)z * NCH + c) * B + b) * 256 + e) * 16 + n;
    float hf = hfin[o];
    float P = __expf(Aa * sumdt[(((size_t)z * NCH + c) * B + b) * 256 + e]);
    hfin[o] = h;                 // becomes h0 for chunk c
    h = fmaf(P, h, hf);
  }
}

// ---------------- scan pass C: replay with h0, fuse +xc*D and *silu(gate); bf16 hi/lo out ----------------
__global__ __launch_bounds__(256) void scan_passC(
    const float* __restrict__ dtg, const float* __restrict__ xc,
    const float* __restrict__ dbl, const float* __restrict__ xz,
    const float* __restrict__ alog, const float* __restrict__ dskip,
    const float* __restrict__ h0, u16* __restrict__ yh, u16* __restrict__ yl) {
  int bc = blockIdx.x;
  int c = bc & (NCH - 1);
  int b = (bc >> 6) & 7;
  int z = bc >> 9;
  int e = threadIdx.x;
  const float* dt_p = dtg + (size_t)z * M * 256;
  const float* xc_p = xc + (size_t)z * M * 256;
  const float* dbl_p = dbl + (size_t)z * M * 48;
  const float* xz_p = xz + (size_t)z * M * 512;
  u16* yh_p = yh + (size_t)z * M * 1024;
  u16* yl_p = yl + (size_t)z * M * 1024;
  const float* al = alog + z * 4096;
  __shared__ float Ssh[LC][32];   // cols [0:16)=B, [16:32)=C
  float Aa[16];
#pragma unroll
  for (int n = 0; n < 16; n++) Aa[n] = -__expf(al[e * 16 + n]);
  {
    int row = e >> 3;
    int colg = (e & 7) * 4;
    int s = c * LC + row;
    int w = z ? (L - 1 - s) : s;
    const float* src = dbl_p + ((size_t)b * L + w) * 48 + 16 + colg;
    float4 v = *(const float4*)src;
    Ssh[row][colg + 0] = v.x; Ssh[row][colg + 1] = v.y;
    Ssh[row][colg + 2] = v.z; Ssh[row][colg + 3] = v.w;
  }
  float h[16];
  size_t ho = ((((size_t)z * NCH + c) * B + b) * 256 + e) * 16;
#pragma unroll
  for (int n = 0; n < 16; n++) h[n] = h0[ho + n];
  float Dv = dskip[z * 256 + e];
  __syncthreads();
  for (int tl = 0; tl < LC; tl++) {
    int s = c * LC + tl;
    int w = z ? (L - 1 - s) : s;
    size_t base = ((size_t)b * L + w) * 256 + e;
    float d = dt_p[base];
    float xv = xc_p[base];
    float zv = xz_p[((size_t)b * L + w) * 512 + 256 + e];
    float du = d * xv;
    float y = 0.f;
#pragma unroll
    for (int n = 0; n < 16; n++) {
      float dA = __expf(d * Aa[n]);
      h[n] = fmaf(dA, h[n], du * Ssh[tl][n]);
      y = fmaf(h[n], Ssh[tl][16 + n], y);
    }
    y = fmaf(xv, Dv, y);
    float g = y * (zv * sigmoidf_(zv));
    u16 hh = bf16_of(g);
    size_t yb = (size_t)(b * L + w) * 1024 + e;
    yh_p[yb] = hh;
    yl_p[yb] = bf16_of(g - bf16_to_f(hh));
  }
}

// ---------------- mean pool (reads bf16 hi/lo seq planes) and classifier head ----------------
__global__ void pool_partial(const u16* __restrict__ sh, const u16* __restrict__ sl,
                             float* __restrict__ pooled) {
  int b = blockIdx.x >> 4;
  int tc = blockIdx.x & 15;
  int e = threadIdx.x;
  float s = 0.f;
  for (int tl = 0; tl < 128; tl++) {
    int t = tc * 128 + tl;
    size_t o = ((size_t)b * L + t) * 256 + e;
    s += bf16_to_f(sh[o]) + bf16_to_f(sl[o]);
  }
  atomicAdd(&pooled[b * 256 + e], s * (1.f / L));
}

__global__ void classify(const float* __restrict__ pooled, const float* __restrict__ cw,
                         const float* __restrict__ cb, float* __restrict__ out) {
  int tid = threadIdx.x;
  if (tid < B * NC) {
    int b = tid / NC, cidx = tid % NC;
    float acc = cb[cidx];
    for (int k = 0; k < 256; k++) acc = fmaf(pooled[b * 256 + k], cw[cidx * 256 + k], acc);
    out[b * NC + cidx] = acc;
  }
}

extern "C" void kernel_launch(void* const* d_in, const int* in_sizes, int n_in,
                              void* d_out, int out_size, void* d_ws, size_t ws_size,
                              hipStream_t stream) {
  const float* x      = (const float*)d_in[0];
  const float* pw     = (const float*)d_in[1];
  const float* pb     = (const float*)d_in[2];
  const float* W_in   = (const float*)d_in[3];
  const float* conv_w = (const float*)d_in[4];
  const float* conv_b = (const float*)d_in[5];
  const float* W_x    = (const float*)d_in[6];
  const float* W_dt   = (const float*)d_in[7];
  const float* b_dt   = (const float*)d_in[8];
  const float* A_log  = (const float*)d_in[9];
  const float* D_skip = (const float*)d_in[10];
  const float* W_out  = (const float*)d_in[11];
  const float* cls_w  = (const float*)d_in[12];
  const float* cls_b  = (const float*)d_in[13];
  float* out = (float*)d_out;

  char* p = (char*)d_ws;
  auto alloc = [&](size_t bytes) {
    void* r = (void*)p;
    p += (bytes + 255) & ~(size_t)255;
    return r;
  };
  u16*   sh     = (u16*)alloc((size_t)M * 256 * 2);
  u16*   sl     = (u16*)alloc((size_t)M * 256 * 2);
  float* xz     = (float*)alloc((size_t)2 * M * 512 * 4);
  float* xc     = (float*)alloc((size_t)2 * M * 256 * 4);
  float* dbl    = (float*)alloc((size_t)2 * M * 48 * 4);
  float* dtg    = (float*)alloc((size_t)2 * M * 256 * 4);
  float* hfin   = (float*)alloc((size_t)2 * NCH * B * 256 * 16 * 4);
  float* sumdt  = (float*)alloc((size_t)2 * NCH * B * 256 * 4);
  float* pooled = (float*)alloc((size_t)B * 256 * 4);
  u16*   winT_h = (u16*)alloc((size_t)4 * 512 * 256 * 2);
  u16*   winT_l = (u16*)alloc((size_t)4 * 512 * 256 * 2);
  u16*   woutT_h= (u16*)alloc((size_t)2 * 256 * 512 * 2);
  u16*   woutT_l= (u16*)alloc((size_t)2 * 256 * 512 * 2);
  // y hi/lo planes overlay the dead xi half of xz rows (u16 cols 0..255 = hi, 256..511 = lo)
  u16* yh = (u16*)xz;
  u16* yl = (u16*)xz + 256;

  prep_weights<<<3072, 256, 0, stream>>>(W_in, W_out, winT_h, winT_l, woutT_h, woutT_l);
  patch_embed<<<M, 256, 0, stream>>>(x, pw, pb, sh, sl);

  for (int i = 0; i < NB; i++) {
    // xz[z] = seq @ W_in[i,z]  (fp32 out; A = seq hi/lo planes, shared across z)
    gemm_mfma<<<dim3(4, M / 128, 2), 256, 0, stream>>>(
        sh, sl, sh, sl, 256, 256,
        winT_h + (size_t)i * 2 * 131072, winT_l + (size_t)i * 2 * 131072, 131072,
        xz, (size_t)M * 512, 512, nullptr, nullptr, 256);
    conv_silu<<<dim3(M, 2), 256, 0, stream>>>(
        xz, conv_w + i * 2 * 1024, conv_b + i * 2 * 256, xc);
    gemm_f32<<<dim3(1, M / 128, 2), 256, 0, stream>>>(
        xc, xc, 256, 256, (size_t)M * 256,
        W_x + (size_t)i * 2 * 256 * 48, (size_t)256 * 48,
        dbl, (size_t)M * 48, 48, 256);
    dt_softplus<<<dim3(M, 2), 256, 0, stream>>>(
        dbl, W_dt + i * 2 * 4096, b_dt + i * 2 * 256, dtg);
    scan_passA<<<2 * B * NCH, 256, 0, stream>>>(
        dtg, xc, dbl, A_log + i * 2 * 4096, hfin, sumdt);
    scan_passB<<<256, 256, 0, stream>>>(hfin, sumdt, A_log + i * 2 * 4096);
    scan_passC<<<2 * B * NCH, 256, 0, stream>>>(
        dtg, xc, dbl, xz, A_log + i * 2 * 4096, D_skip + i * 2 * 256, hfin, yh, yl);
    // seq' = [y_fwd | y_rev] @ [W_out[i,0]; W_out[i,1]]  -> bf16 hi/lo planes sh/sl
    gemm_mfma<<<dim3(2, M / 128, 1), 256, 0, stream>>>(
        yh, yl, yh + (size_t)M * 1024, yl + (size_t)M * 1024, 1024, 256,
        woutT_h + (size_t)i * 131072, woutT_l + (size_t)i * 131072, 0,
        nullptr, 0, 256, sh, sl, 512);
  }
  hipMemsetAsync(pooled, 0, B * 256 * 4, stream);
  pool_partial<<<B * 16, 256, 0, stream>>>(sh, sl, pooled);
  classify<<<1, 128, 0, stream>>>(pooled, cls_w, cls_b, out);
}